// Round 3
// baseline (636.957 us; speedup 1.0000x reference)
//
#include <hip/hip_runtime.h>
#include <hip/hip_fp16.h>

#define M_TOTAL 4096
#define N_TOTAL 11008
#define K_TOTAL 4096
#define KPACK   2048     // int32 cols; each int32 holds ONE byte = 2 nibbles

typedef _Float16 f16x4 __attribute__((ext_vector_type(4)));
typedef _Float16 f16x8 __attribute__((ext_vector_type(8)));
typedef float    f32x4 __attribute__((ext_vector_type(4)));

// ---------------- async 16B global -> LDS ----------------
__device__ __forceinline__ void load16_to_lds(const void* g, void* l) {
    __builtin_amdgcn_global_load_lds(
        (const __attribute__((address_space(1))) unsigned int*)g,
        (__attribute__((address_space(3))) unsigned int*)l,
        16, 0, 0);
}

// ---------------- prepass 1: x fp32 -> f16 (16.7M elems, 8/thread) ----------------
__global__ __launch_bounds__(256)
void _Int4Linear_cvt_x(const float* __restrict__ x, _Float16* __restrict__ xf) {
    const size_t i = ((size_t)blockIdx.x * 256 + threadIdx.x) * 8;
    const float4 v0 = *(const float4*)(x + i);
    const float4 v1 = *(const float4*)(x + i + 4);
    f16x8 h = { (_Float16)v0.x, (_Float16)v0.y, (_Float16)v0.z, (_Float16)v0.w,
                (_Float16)v1.x, (_Float16)v1.y, (_Float16)v1.z, (_Float16)v1.w };
    *(f16x8*)(xf + i) = h;
}

// ---------------- prepass 2: wp int32 -> f16 pairs (22.5M int32, 4/thread) ----------------
__global__ __launch_bounds__(256)
void _Int4Linear_dequant_w(const int* __restrict__ wp, _Float16* __restrict__ wf) {
    const size_t i = ((size_t)blockIdx.x * 256 + threadIdx.x) * 4;   // int32 index
    const int4 p = *(const int4*)(wp + i);
    const int v[4] = { p.x, p.y, p.z, p.w };
    f16x8 h;
    #pragma unroll
    for (int j = 0; j < 4; ++j) {
        h[2 * j]     = (_Float16)(( v[j]       & 15) - 8);
        h[2 * j + 1] = (_Float16)(((v[j] >> 4) & 15) - 8);
    }
    *(f16x8*)(wf + i * 2) = h;   // each int32 -> 2 f16
}

// ---------------- main GEMM: 256x256 tile, 8-phase counted-vmcnt schedule ----------------
// 512 threads = 8 waves (2M x 4N). BK=64 as two 32-half K-slots, double-buffered:
// LDS = A[4 slots x 16KB] + B[4 slots x 16KB] = 128 KB (dynamic, needs attr).
// Slot layout: 256 rows x 32 halves (64B rows), chunk-XOR swizzled:
//   physical 16B chunk p at row r holds logical chunk p ^ ((r>>1)&3)
// written via pre-swizzled GLOBAL source (LDS dest linear, as global_load_lds requires),
// read with the same XOR -> conflict-free ds_read_b128 (R2: SQ_LDS_BANK_CONFLICT = 0).
//
// R3 change: DEEPER PREFETCH. All nxp slots are free from ph0 of iter t (last read in
// t-1), so the whole next-tile k0-pair is issued at ph0, An1 at ph1, Bn1 at ph2.
// Rendezvous: end-ph1 vmcnt(6) waits this tile's k1 pair (issued prev ph1/ph2, ~4-5
// phases ago); end-ph3 vmcnt(4) waits next tile's k0 pair (issued ph0, ~4 phases ago).
// Issue->wait distance now ~800-1000 cyc, covering HBM/L2-miss latency (~900 cyc).
#define BM 256
#define BN 256
#define NKT 64          // K / 64

__global__ __launch_bounds__(512, 2)
void _Int4Linear_54631984005366_kernel(const _Float16* __restrict__ A,   // [M][K] f16
                                       const _Float16* __restrict__ B,   // [N][K] f16
                                       const float* __restrict__ scale,
                                       const float* __restrict__ bias,
                                       float*       __restrict__ out)
{
    extern __shared__ char sm[];
    char* const smA = sm;              // slot(par,kh) = smA + ((par+kh)<<14)
    char* const smB = sm + 65536;

    const int t    = threadIdx.x;
    const int wave = t >> 6;
    const int lane = t & 63;
    const int l16  = lane & 15;
    const int quad = lane >> 4;
    const int wm   = wave >> 2;        // 0..1
    const int wn   = wave & 3;         // 0..3

    // XCD-aware bijective swizzle: 688 = 8 * 86 exactly; nT-major (16 consecutive share B-panel)
    const int b0 = blockIdx.x;
    const int sw = (b0 & 7) * 86 + (b0 >> 3);
    const int mBase = (sw & 15) * BM;   // 16 m-tiles
    const int nBase = (sw >> 4) * BN;   // 43 n-tiles

    // staging: round r covers rows r*128; wave covers 16 rows (1KB), lane -> (row, chunk)
    // source chunk pre-swizzled: (lane&3) ^ ((lane>>3)&3)  == chunk ^ ((row>>1)&3)
    const int srow = wave * 16 + (lane >> 2);
    const int scol = (((lane & 3) ^ ((lane >> 3) & 3)) << 3);   // halves
    const _Float16* const Ab = A + (size_t)(mBase + srow) * K_TOTAL + scol;
    const _Float16* const Bb = B + (size_t)(nBase + srow) * K_TOTAL + scol;
    const int ldst = wave * 1024;      // + r*8192 within slot (linear dest)

    // ds_read byte offsets within a slot (swizzled chunk)
    const int chA  = (quad ^ ((l16 >> 1) & 3)) << 4;
    const int aoff = (wm * 128 + l16) * 64 + chA;
    const int boff = (wn * 64  + l16) * 64 + chA;

    f32x4 acc[8][4] = {};

    // ---- prologue: stage K-tile 0 into parity-0 slots, order A-k0, B-k0, A-k1, B-k1 ----
    #pragma unroll
    for (int r = 0; r < 2; ++r) load16_to_lds(Ab + (size_t)r * 128 * K_TOTAL,      smA + r * 8192 + ldst);
    #pragma unroll
    for (int r = 0; r < 2; ++r) load16_to_lds(Bb + (size_t)r * 128 * K_TOTAL,      smB + r * 8192 + ldst);
    #pragma unroll
    for (int r = 0; r < 2; ++r) load16_to_lds(Ab + (size_t)r * 128 * K_TOTAL + 32, smA + 16384 + r * 8192 + ldst);
    #pragma unroll
    for (int r = 0; r < 2; ++r) load16_to_lds(Bb + (size_t)r * 128 * K_TOTAL + 32, smB + 16384 + r * 8192 + ldst);
    asm volatile("s_waitcnt vmcnt(4)" ::: "memory");   // A-k0,B-k0 landed (own wave); barrier = all waves
    __builtin_amdgcn_s_barrier();
    asm volatile("" ::: "memory");

    #pragma unroll 2
    for (int t0 = 0; t0 < NKT; ++t0) {
        const int par = (t0 & 1) * 2;
        const int nxp = ((t0 + 1) & 1) * 2;
        const int tn  = (t0 < NKT - 1) ? (t0 + 1) : t0;   // clamp: last segment re-stages (never read)
        const int kn  = tn * 64;                          // halves
        char* const Ac0 = smA + (par    ) * 16384;
        char* const Ac1 = smA + (par + 1) * 16384;
        char* const Bc0 = smB + (par    ) * 16384;
        char* const Bc1 = smB + (par + 1) * 16384;
        char* const An0 = smA + (nxp    ) * 16384;
        char* const An1 = smA + (nxp + 1) * 16384;
        char* const Bn0 = smB + (nxp    ) * 16384;
        char* const Bn1 = smB + (nxp + 1) * 16384;

        f16x8 a[4], b[4];

        // ---------- phase 0: kh0, m-frags 0-3; stages next-tile k0 PAIR (A+B, 4 loads) ----------
        #pragma unroll
        for (int f = 0; f < 4; ++f) a[f] = *(const f16x8*)(Ac0 + aoff + f * 1024);
        #pragma unroll
        for (int f = 0; f < 4; ++f) b[f] = *(const f16x8*)(Bc0 + boff + f * 1024);
        #pragma unroll
        for (int r = 0; r < 2; ++r) load16_to_lds(Ab + (size_t)r * 128 * K_TOTAL + kn, An0 + r * 8192 + ldst);
        #pragma unroll
        for (int r = 0; r < 2; ++r) load16_to_lds(Bb + (size_t)r * 128 * K_TOTAL + kn, Bn0 + r * 8192 + ldst);
        __builtin_amdgcn_s_barrier();
        asm volatile("s_waitcnt lgkmcnt(0)" ::: "memory");
        __builtin_amdgcn_sched_barrier(0);
        __builtin_amdgcn_s_setprio(1);
        #pragma unroll
        for (int mf = 0; mf < 4; ++mf)
            #pragma unroll
            for (int nf = 0; nf < 4; ++nf)
                acc[mf][nf] = __builtin_amdgcn_mfma_f32_16x16x32_f16(a[mf], b[nf], acc[mf][nf], 0, 0, 0);
        __builtin_amdgcn_s_setprio(0);
        __builtin_amdgcn_s_barrier();          // frees B-k0 (b held in regs)
        asm volatile("" ::: "memory");

        // ---------- phase 1: kh0, m-frags 4-7 (reuse b); stages next A-k1 ----------
        #pragma unroll
        for (int f = 0; f < 4; ++f) a[f] = *(const f16x8*)(Ac0 + aoff + 4096 + f * 1024);
        #pragma unroll
        for (int r = 0; r < 2; ++r) load16_to_lds(Ab + (size_t)r * 128 * K_TOTAL + kn + 32, An1 + r * 8192 + ldst);
        __builtin_amdgcn_s_barrier();
        asm volatile("s_waitcnt lgkmcnt(0)" ::: "memory");
        __builtin_amdgcn_sched_barrier(0);
        __builtin_amdgcn_s_setprio(1);
        #pragma unroll
        for (int mf = 0; mf < 4; ++mf)
            #pragma unroll
            for (int nf = 0; nf < 4; ++nf)
                acc[4 + mf][nf] = __builtin_amdgcn_mfma_f32_16x16x32_f16(a[mf], b[nf], acc[4 + mf][nf], 0, 0, 0);
        __builtin_amdgcn_s_setprio(0);
        // this tile's k1 pair (issued prev iter ph1/ph2; prologue A1,B1 for t0=0) landed:
        // newer outstanding = ph0 (4) + ph1 (2) = 6
        asm volatile("s_waitcnt vmcnt(6)" ::: "memory");
        __builtin_amdgcn_s_barrier();          // rendezvous -> all waves' k1 landed; frees A-k0
        asm volatile("" ::: "memory");

        // ---------- phase 2: kh1, m-frags 0-3; stages next B-k1 ----------
        #pragma unroll
        for (int f = 0; f < 4; ++f) a[f] = *(const f16x8*)(Ac1 + aoff + f * 1024);
        #pragma unroll
        for (int f = 0; f < 4; ++f) b[f] = *(const f16x8*)(Bc1 + boff + f * 1024);
        #pragma unroll
        for (int r = 0; r < 2; ++r) load16_to_lds(Bb + (size_t)r * 128 * K_TOTAL + kn + 32, Bn1 + r * 8192 + ldst);
        __builtin_amdgcn_s_barrier();
        asm volatile("s_waitcnt lgkmcnt(0)" ::: "memory");
        __builtin_amdgcn_sched_barrier(0);
        __builtin_amdgcn_s_setprio(1);
        #pragma unroll
        for (int mf = 0; mf < 4; ++mf)
            #pragma unroll
            for (int nf = 0; nf < 4; ++nf)
                acc[mf][nf] = __builtin_amdgcn_mfma_f32_16x16x32_f16(a[mf], b[nf], acc[mf][nf], 0, 0, 0);
        __builtin_amdgcn_s_setprio(0);
        __builtin_amdgcn_s_barrier();          // frees B-k1
        asm volatile("" ::: "memory");

        // ---------- phase 3: kh1, m-frags 4-7 (reuse b); no staging ----------
        #pragma unroll
        for (int f = 0; f < 4; ++f) a[f] = *(const f16x8*)(Ac1 + aoff + 4096 + f * 1024);
        __builtin_amdgcn_s_barrier();
        asm volatile("s_waitcnt lgkmcnt(0)" ::: "memory");
        __builtin_amdgcn_sched_barrier(0);
        __builtin_amdgcn_s_setprio(1);
        #pragma unroll
        for (int mf = 0; mf < 4; ++mf)
            #pragma unroll
            for (int nf = 0; nf < 4; ++nf)
                acc[4 + mf][nf] = __builtin_amdgcn_mfma_f32_16x16x32_f16(a[mf], b[nf], acc[4 + mf][nf], 0, 0, 0);
        __builtin_amdgcn_s_setprio(0);
        // next tile's k0 pair (issued this ph0) landed: newer = ph1 (2) + ph2 (2) = 4
        asm volatile("s_waitcnt vmcnt(4)" ::: "memory");
        __builtin_amdgcn_s_barrier();          // rendezvous; frees A-k1; next ph0 reads safe
        asm volatile("" ::: "memory");
    }
    asm volatile("s_waitcnt vmcnt(0)" ::: "memory");   // drain stray last-segment stages before exit

    // ---- epilogue: scale/bias fused, C[m][n] with col=l16, row=quad*4+r ----
    #pragma unroll
    for (int nf = 0; nf < 4; ++nf) {
        const int n = nBase + wn * 64 + nf * 16 + l16;
        const float s  = scale[n];
        const float bz = bias[n];
        #pragma unroll
        for (int mf = 0; mf < 8; ++mf) {
            const int mb = mBase + wm * 128 + mf * 16 + quad * 4;
            #pragma unroll
            for (int r = 0; r < 4; ++r)
                out[(size_t)(mb + r) * N_TOTAL + n] = acc[mf][nf][r] * s + bz;
        }
    }
}

// ---------------- fallback: self-contained (raw inputs, static 20KB LDS, no attrs) ----------------
#define FBM 128
#define FBN 128
#define FBK 32
#define LDR 40
__global__ __launch_bounds__(256)
void _Int4Linear_fallback(const float* __restrict__ x, const int* __restrict__ wp,
                          const float* __restrict__ scale, const float* __restrict__ bias,
                          float* __restrict__ out)
{
    __shared__ _Float16 As[FBM * LDR];
    __shared__ _Float16 Bs[FBN * LDR];
    const int t = threadIdx.x, wave = t >> 6, lane = t & 63;
    const int l16 = lane & 15, quad = lane >> 4;
    const int nBase = blockIdx.x * FBN, mBase = blockIdx.y * FBM;
    const int wm = (wave >> 1) * 64, wn = (wave & 1) * 64;
    f32x4 acc[4][4] = {};
    for (int k0 = 0; k0 < K_TOTAL; k0 += FBK) {
        #pragma unroll
        for (int i = 0; i < 4; ++i) {
            const int li = i * 256 + t, row = li >> 3, c4 = li & 7;
            const float4 v = *(const float4*)(&x[(size_t)(mBase + row) * K_TOTAL + k0 + c4 * 4]);
            f16x4 hv = { (_Float16)v.x, (_Float16)v.y, (_Float16)v.z, (_Float16)v.w };
            *(f16x4*)(&As[row * LDR + c4 * 4]) = hv;
        }
        #pragma unroll
        for (int i = 0; i < 2; ++i) {
            const int li = i * 256 + t, row = li >> 2, c4 = li & 3;
            const int4 p = *(const int4*)(&wp[(size_t)(nBase + row) * KPACK + (k0 >> 1) + c4 * 4]);
            const int vals[4] = { p.x, p.y, p.z, p.w };
            f16x8 hv;
            #pragma unroll
            for (int j = 0; j < 4; ++j) {
                hv[2 * j]     = (_Float16)(( vals[j]       & 15) - 8);
                hv[2 * j + 1] = (_Float16)(((vals[j] >> 4) & 15) - 8);
            }
            *(f16x8*)(&Bs[row * LDR + c4 * 8]) = hv;
        }
        __syncthreads();
        f16x8 a[4], b[4];
        #pragma unroll
        for (int mt = 0; mt < 4; ++mt)
            a[mt] = *(const f16x8*)(&As[(wm + mt * 16 + l16) * LDR + quad * 8]);
        #pragma unroll
        for (int nt = 0; nt < 4; ++nt)
            b[nt] = *(const f16x8*)(&Bs[(wn + nt * 16 + l16) * LDR + quad * 8]);
        #pragma unroll
        for (int mt = 0; mt < 4; ++mt)
            #pragma unroll
            for (int nt = 0; nt < 4; ++nt)
                acc[mt][nt] = __builtin_amdgcn_mfma_f32_16x16x32_f16(a[mt], b[nt], acc[mt][nt], 0, 0, 0);
        __syncthreads();
    }
    #pragma unroll
    for (int nt = 0; nt < 4; ++nt) {
        const int n = nBase + wn + nt * 16 + l16;
        const float s = scale[n], bz = bias[n];
        #pragma unroll
        for (int mt = 0; mt < 4; ++mt)
            #pragma unroll
            for (int r = 0; r < 4; ++r)
                out[(size_t)(mBase + wm + mt * 16 + quad * 4 + r) * N_TOTAL + n] = acc[mt][nt][r] * s + bz;
    }
}

extern "C" void kernel_launch(void* const* d_in, const int* in_sizes, int n_in,
                              void* d_out, int out_size, void* d_ws, size_t ws_size,
                              hipStream_t stream) {
    const float* x     = (const float*)d_in[0];
    const int*   wp    = (const int*)d_in[1];
    const float* scale = (const float*)d_in[2];
    const float* bias  = (const float*)d_in[3];
    float*       out   = (float*)d_out;

    const size_t xf_bytes = (size_t)M_TOTAL * K_TOTAL * 2;              // 32 MB
    const size_t wf_bytes = (size_t)N_TOTAL * K_TOTAL * 2;              // 86 MB

    // Tri-state: 0 = untried, 1 = 128KB dynamic-LDS enabled, -1 = failed -> fallback.
    static int lds_attr_state = 0;
    if (lds_attr_state == 0) {
        hipError_t e = hipFuncSetAttribute(
            (const void*)_Int4Linear_54631984005366_kernel,
            hipFuncAttributeMaxDynamicSharedMemorySize, 131072);
        lds_attr_state = (e == hipSuccess) ? 1 : -1;
    }

    if (ws_size >= xf_bytes + wf_bytes && lds_attr_state == 1) {
        _Float16* xf = (_Float16*)d_ws;
        _Float16* wf = (_Float16*)((char*)d_ws + xf_bytes);
        // prepass: 16,777,216 floats / 8 per thread = 8192 blocks
        _Int4Linear_cvt_x<<<8192, 256, 0, stream>>>(x, xf);
        // prepass: 22,544,384 int32 / 4 per thread = 22016 blocks
        _Int4Linear_dequant_w<<<22016, 256, 0, stream>>>(wp, wf);
        // 16 m-tiles x 43 n-tiles = 688 blocks (exactly 8*86 -> clean XCD swizzle)
        _Int4Linear_54631984005366_kernel<<<dim3(688), dim3(512), 131072, stream>>>(xf, wf, scale, bias, out);
    } else {
        dim3 grid(N_TOTAL / FBN, M_TOTAL / FBM);
        _Int4Linear_fallback<<<grid, 256, 0, stream>>>(x, wp, scale, bias, out);
    }
}

// Round 4
// 620.702 us; speedup vs baseline: 1.0262x; 1.0262x over previous
//
#include <hip/hip_runtime.h>
#include <hip/hip_fp16.h>

#define M_TOTAL 4096
#define N_TOTAL 11008
#define K_TOTAL 4096
#define KPACK   2048     // int32 cols; each int32 holds ONE byte = 2 nibbles

typedef _Float16 f16x4 __attribute__((ext_vector_type(4)));
typedef _Float16 f16x8 __attribute__((ext_vector_type(8)));
typedef float    f32x4 __attribute__((ext_vector_type(4)));

// ---------------- async 16B global -> LDS ----------------
__device__ __forceinline__ void load16_to_lds(const void* g, void* l) {
    __builtin_amdgcn_global_load_lds(
        (const __attribute__((address_space(1))) unsigned int*)g,
        (__attribute__((address_space(3))) unsigned int*)l,
        16, 0, 0);
}

// ---------------- prepass 1: x fp32 -> f16 (16.7M elems, 8/thread) ----------------
__global__ __launch_bounds__(256)
void _Int4Linear_cvt_x(const float* __restrict__ x, _Float16* __restrict__ xf) {
    const size_t i = ((size_t)blockIdx.x * 256 + threadIdx.x) * 8;
    const float4 v0 = *(const float4*)(x + i);
    const float4 v1 = *(const float4*)(x + i + 4);
    f16x8 h = { (_Float16)v0.x, (_Float16)v0.y, (_Float16)v0.z, (_Float16)v0.w,
                (_Float16)v1.x, (_Float16)v1.y, (_Float16)v1.z, (_Float16)v1.w };
    *(f16x8*)(xf + i) = h;
}

// ---------------- prepass 2: wp int32 -> f16 pairs (22.5M int32, 4/thread) ----------------
__global__ __launch_bounds__(256)
void _Int4Linear_dequant_w(const int* __restrict__ wp, _Float16* __restrict__ wf) {
    const size_t i = ((size_t)blockIdx.x * 256 + threadIdx.x) * 4;   // int32 index
    const int4 p = *(const int4*)(wp + i);
    const int v[4] = { p.x, p.y, p.z, p.w };
    f16x8 h;
    #pragma unroll
    for (int j = 0; j < 4; ++j) {
        h[2 * j]     = (_Float16)(( v[j]       & 15) - 8);
        h[2 * j + 1] = (_Float16)(((v[j] >> 4) & 15) - 8);
    }
    *(f16x8*)(wf + i * 2) = h;   // each int32 -> 2 f16
}

// ---------------- main GEMM: 256x256 tile, 2-phase compiler-interleaved schedule ----------------
// 512 threads = 8 waves (2M x 4N). BK=64 as two 32-half K-slots, double-buffered:
// LDS = A[4 slots x 16KB] + B[4 slots x 16KB] = 128 KB (dynamic, needs attr).
// Slot layout: 256 rows x 32 halves (64B rows), chunk-XOR swizzled (R2: 0 bank conflicts).
//
// R4 change: KILL THE READ/MFMA SERIALIZATION. R2/R3's dual-barrier phases forced all
// waves to ds_read-burst (~565 cyc/CU) then MFMA-burst (~620 cyc/CU) in lockstep ->
// 52% pipe cap x 0.90 tail = the measured 43-44% MfmaUtil. Now each kh-half is ONE
// region: {issue 4 stages; issue 12 frag reads; 32 MFMA} with NO lgkmcnt(0) drain --
// the compiler emits counted lgkmcnt so MFMA runs while the LDS pipe drains the
// remaining reads. One vmcnt(4)+barrier per phase (counted, never 0 in loop).
//   end-A: waits curr k1 pair (issued prev phase B);  end-B: waits next k0 pair
//   (issued this phase A) -- 1-phase distance (~1200 cyc) covers HBM latency.
#define BM 256
#define BN 256
#define NKT 64          // K / 64

__global__ __launch_bounds__(512, 2)
void _Int4Linear_54631984005366_kernel(const _Float16* __restrict__ A,   // [M][K] f16
                                       const _Float16* __restrict__ B,   // [N][K] f16
                                       const float* __restrict__ scale,
                                       const float* __restrict__ bias,
                                       float*       __restrict__ out)
{
    extern __shared__ char sm[];
    char* const smA = sm;              // slot(par+kh) = smA + ((par+kh)<<14)
    char* const smB = sm + 65536;

    const int t    = threadIdx.x;
    const int wave = t >> 6;
    const int lane = t & 63;
    const int l16  = lane & 15;
    const int quad = lane >> 4;
    const int wm   = wave >> 2;        // 0..1
    const int wn   = wave & 3;         // 0..3

    // XCD-aware bijective swizzle: 688 = 8 * 86 exactly; nT-major (16 consecutive share B-panel)
    const int b0 = blockIdx.x;
    const int sw = (b0 & 7) * 86 + (b0 >> 3);
    const int mBase = (sw & 15) * BM;   // 16 m-tiles
    const int nBase = (sw >> 4) * BN;   // 43 n-tiles

    // staging: round r covers rows r*128; wave covers 16 rows (1KB), lane -> (row, chunk)
    // source chunk pre-swizzled: (lane&3) ^ ((lane>>3)&3)  == chunk ^ ((row>>1)&3)
    const int srow = wave * 16 + (lane >> 2);
    const int scol = (((lane & 3) ^ ((lane >> 3) & 3)) << 3);   // halves
    const _Float16* const Ab = A + (size_t)(mBase + srow) * K_TOTAL + scol;
    const _Float16* const Bb = B + (size_t)(nBase + srow) * K_TOTAL + scol;
    const int ldst = wave * 1024;      // + r*8192 within slot (linear dest)

    // ds_read byte offsets within a slot (swizzled chunk)
    const int chA  = (quad ^ ((l16 >> 1) & 3)) << 4;
    const int aoff = (wm * 128 + l16) * 64 + chA;
    const int boff = (wn * 64  + l16) * 64 + chA;

    f32x4 acc[8][4] = {};

    // ---- prologue: stage K-tile 0, order A-k0, B-k0, A-k1, B-k1 (8 loads) ----
    #pragma unroll
    for (int r = 0; r < 2; ++r) load16_to_lds(Ab + (size_t)r * 128 * K_TOTAL,      smA + r * 8192 + ldst);
    #pragma unroll
    for (int r = 0; r < 2; ++r) load16_to_lds(Bb + (size_t)r * 128 * K_TOTAL,      smB + r * 8192 + ldst);
    #pragma unroll
    for (int r = 0; r < 2; ++r) load16_to_lds(Ab + (size_t)r * 128 * K_TOTAL + 32, smA + 16384 + r * 8192 + ldst);
    #pragma unroll
    for (int r = 0; r < 2; ++r) load16_to_lds(Bb + (size_t)r * 128 * K_TOTAL + 32, smB + 16384 + r * 8192 + ldst);
    asm volatile("s_waitcnt vmcnt(4)" ::: "memory");   // k0 pair landed (own wave); barrier = all waves
    __builtin_amdgcn_s_barrier();
    __builtin_amdgcn_sched_barrier(0);

    #pragma unroll 2
    for (int t0 = 0; t0 < NKT; ++t0) {
        const int par = (t0 & 1) * 2;
        const int nxp = ((t0 + 1) & 1) * 2;
        const int tn  = (t0 < NKT - 1) ? (t0 + 1) : t0;   // clamp: last segment re-stages (never read)
        const int kn  = tn * 64;                          // halves
        char* const Ac0 = smA + (par    ) * 16384;
        char* const Ac1 = smA + (par + 1) * 16384;
        char* const Bc0 = smB + (par    ) * 16384;
        char* const Bc1 = smB + (par + 1) * 16384;
        char* const An0 = smA + (nxp    ) * 16384;
        char* const An1 = smA + (nxp + 1) * 16384;
        char* const Bn0 = smB + (nxp    ) * 16384;
        char* const Bn1 = smB + (nxp + 1) * 16384;

        // ========== phase A: kh0 -- stages next k0 pair; reads Ac0/Bc0; 32 MFMA ==========
        {
            #pragma unroll
            for (int r = 0; r < 2; ++r) load16_to_lds(Ab + (size_t)r * 128 * K_TOTAL + kn, An0 + r * 8192 + ldst);
            #pragma unroll
            for (int r = 0; r < 2; ++r) load16_to_lds(Bb + (size_t)r * 128 * K_TOTAL + kn, Bn0 + r * 8192 + ldst);
            f16x8 a[8], b[4];
            #pragma unroll
            for (int f = 0; f < 8; ++f) a[f] = *(const f16x8*)(Ac0 + aoff + f * 1024);
            #pragma unroll
            for (int f = 0; f < 4; ++f) b[f] = *(const f16x8*)(Bc0 + boff + f * 1024);
            __builtin_amdgcn_s_setprio(1);
            #pragma unroll
            for (int mf = 0; mf < 8; ++mf)
                #pragma unroll
                for (int nf = 0; nf < 4; ++nf)
                    acc[mf][nf] = __builtin_amdgcn_mfma_f32_16x16x32_f16(a[mf], b[nf], acc[mf][nf], 0, 0, 0);
            __builtin_amdgcn_s_setprio(0);
            // curr k1 pair (issued prev phase B; prologue for t0=0) landed: newer = this phase's 4
            asm volatile("s_waitcnt vmcnt(4)" ::: "memory");
            __builtin_amdgcn_s_barrier();
            __builtin_amdgcn_sched_barrier(0);
        }

        // ========== phase B: kh1 -- stages next k1 pair; reads Ac1/Bc1; 32 MFMA ==========
        {
            #pragma unroll
            for (int r = 0; r < 2; ++r) load16_to_lds(Ab + (size_t)r * 128 * K_TOTAL + kn + 32, An1 + r * 8192 + ldst);
            #pragma unroll
            for (int r = 0; r < 2; ++r) load16_to_lds(Bb + (size_t)r * 128 * K_TOTAL + kn + 32, Bn1 + r * 8192 + ldst);
            f16x8 a[8], b[4];
            #pragma unroll
            for (int f = 0; f < 8; ++f) a[f] = *(const f16x8*)(Ac1 + aoff + f * 1024);
            #pragma unroll
            for (int f = 0; f < 4; ++f) b[f] = *(const f16x8*)(Bc1 + boff + f * 1024);
            __builtin_amdgcn_s_setprio(1);
            #pragma unroll
            for (int mf = 0; mf < 8; ++mf)
                #pragma unroll
                for (int nf = 0; nf < 4; ++nf)
                    acc[mf][nf] = __builtin_amdgcn_mfma_f32_16x16x32_f16(a[mf], b[nf], acc[mf][nf], 0, 0, 0);
            __builtin_amdgcn_s_setprio(0);
            // next k0 pair (issued this phase A) landed: newer = this phase's 4
            asm volatile("s_waitcnt vmcnt(4)" ::: "memory");
            __builtin_amdgcn_s_barrier();
            __builtin_amdgcn_sched_barrier(0);
        }
    }
    asm volatile("s_waitcnt vmcnt(0)" ::: "memory");   // drain stray last-segment stages before exit

    // ---- epilogue: scale/bias fused, C[m][n] with col=l16, row=quad*4+r ----
    #pragma unroll
    for (int nf = 0; nf < 4; ++nf) {
        const int n = nBase + wn * 64 + nf * 16 + l16;
        const float s  = scale[n];
        const float bz = bias[n];
        #pragma unroll
        for (int mf = 0; mf < 8; ++mf) {
            const int mb = mBase + wm * 128 + mf * 16 + quad * 4;
            #pragma unroll
            for (int r = 0; r < 4; ++r)
                out[(size_t)(mb + r) * N_TOTAL + n] = acc[mf][nf][r] * s + bz;
        }
    }
}

// ---------------- fallback: self-contained (raw inputs, static 20KB LDS, no attrs) ----------------
#define FBM 128
#define FBN 128
#define FBK 32
#define LDR 40
__global__ __launch_bounds__(256)
void _Int4Linear_fallback(const float* __restrict__ x, const int* __restrict__ wp,
                          const float* __restrict__ scale, const float* __restrict__ bias,
                          float* __restrict__ out)
{
    __shared__ _Float16 As[FBM * LDR];
    __shared__ _Float16 Bs[FBN * LDR];
    const int t = threadIdx.x, wave = t >> 6, lane = t & 63;
    const int l16 = lane & 15, quad = lane >> 4;
    const int nBase = blockIdx.x * FBN, mBase = blockIdx.y * FBM;
    const int wm = (wave >> 1) * 64, wn = (wave & 1) * 64;
    f32x4 acc[4][4] = {};
    for (int k0 = 0; k0 < K_TOTAL; k0 += FBK) {
        #pragma unroll
        for (int i = 0; i < 4; ++i) {
            const int li = i * 256 + t, row = li >> 3, c4 = li & 7;
            const float4 v = *(const float4*)(&x[(size_t)(mBase + row) * K_TOTAL + k0 + c4 * 4]);
            f16x4 hv = { (_Float16)v.x, (_Float16)v.y, (_Float16)v.z, (_Float16)v.w };
            *(f16x4*)(&As[row * LDR + c4 * 4]) = hv;
        }
        #pragma unroll
        for (int i = 0; i < 2; ++i) {
            const int li = i * 256 + t, row = li >> 2, c4 = li & 3;
            const int4 p = *(const int4*)(&wp[(size_t)(nBase + row) * KPACK + (k0 >> 1) + c4 * 4]);
            const int vals[4] = { p.x, p.y, p.z, p.w };
            f16x8 hv;
            #pragma unroll
            for (int j = 0; j < 4; ++j) {
                hv[2 * j]     = (_Float16)(( vals[j]       & 15) - 8);
                hv[2 * j + 1] = (_Float16)(((vals[j] >> 4) & 15) - 8);
            }
            *(f16x8*)(&Bs[row * LDR + c4 * 8]) = hv;
        }
        __syncthreads();
        f16x8 a[4], b[4];
        #pragma unroll
        for (int mt = 0; mt < 4; ++mt)
            a[mt] = *(const f16x8*)(&As[(wm + mt * 16 + l16) * LDR + quad * 8]);
        #pragma unroll
        for (int nt = 0; nt < 4; ++nt)
            b[nt] = *(const f16x8*)(&Bs[(wn + nt * 16 + l16) * LDR + quad * 8]);
        #pragma unroll
        for (int mt = 0; mt < 4; ++mt)
            #pragma unroll
            for (int nt = 0; nt < 4; ++nt)
                acc[mt][nt] = __builtin_amdgcn_mfma_f32_16x16x32_f16(a[mt], b[nt], acc[mt][nt], 0, 0, 0);
        __syncthreads();
    }
    #pragma unroll
    for (int nt = 0; nt < 4; ++nt) {
        const int n = nBase + wn + nt * 16 + l16;
        const float s = scale[n], bz = bias[n];
        #pragma unroll
        for (int mt = 0; mt < 4; ++mt)
            #pragma unroll
            for (int r = 0; r < 4; ++r)
                out[(size_t)(mBase + wm + mt * 16 + quad * 4 + r) * N_TOTAL + n] = acc[mt][nt][r] * s + bz;
    }
}

extern "C" void kernel_launch(void* const* d_in, const int* in_sizes, int n_in,
                              void* d_out, int out_size, void* d_ws, size_t ws_size,
                              hipStream_t stream) {
    const float* x     = (const float*)d_in[0];
    const int*   wp    = (const int*)d_in[1];
    const float* scale = (const float*)d_in[2];
    const float* bias  = (const float*)d_in[3];
    float*       out   = (float*)d_out;

    const size_t xf_bytes = (size_t)M_TOTAL * K_TOTAL * 2;              // 32 MB
    const size_t wf_bytes = (size_t)N_TOTAL * K_TOTAL * 2;              // 86 MB

    // Tri-state: 0 = untried, 1 = 128KB dynamic-LDS enabled, -1 = failed -> fallback.
    static int lds_attr_state = 0;
    if (lds_attr_state == 0) {
        hipError_t e = hipFuncSetAttribute(
            (const void*)_Int4Linear_54631984005366_kernel,
            hipFuncAttributeMaxDynamicSharedMemorySize, 131072);
        lds_attr_state = (e == hipSuccess) ? 1 : -1;
    }

    if (ws_size >= xf_bytes + wf_bytes && lds_attr_state == 1) {
        _Float16* xf = (_Float16*)d_ws;
        _Float16* wf = (_Float16*)((char*)d_ws + xf_bytes);
        // prepass: 16,777,216 floats / 8 per thread = 8192 blocks
        _Int4Linear_cvt_x<<<8192, 256, 0, stream>>>(x, xf);
        // prepass: 22,544,384 int32 / 4 per thread = 22016 blocks
        _Int4Linear_dequant_w<<<22016, 256, 0, stream>>>(wp, wf);
        // 16 m-tiles x 43 n-tiles = 688 blocks (exactly 8*86 -> clean XCD swizzle)
        _Int4Linear_54631984005366_kernel<<<dim3(688), dim3(512), 131072, stream>>>(xf, wf, scale, bias, out);
    } else {
        dim3 grid(N_TOTAL / FBN, M_TOTAL / FBM);
        _Int4Linear_fallback<<<grid, 256, 0, stream>>>(x, wp, scale, bias, out);
    }
}